// Round 8
// baseline (90.657 us; speedup 1.0000x reference)
//
#include <hip/hip_runtime.h>
#include <stdint.h>

// LIF neuron scan: B=16, S=2048, D=1024, fp32. NUMERICS FROZEN (absmax 0.0):
// XLA-contracted fp32 — __builtin_fmaf at syn/mem/tha sites, contract(off)
// elsewhere; selects are value-identical to mul-by-{0,1}. DO NOT change step().
//
// R7 post-mortem: ~88us invariant across 3 structures = common per-step stall.
// Self-inflicted drains: asm lgkmcnt(0) serialized 64 ds_reads vs compute;
// vmcnt(16) force-retired 48 fresh stores per tile.
// R8: stall-free single wave:
//   - TRIPLE-buffered LDS (48KB), prefetch distance 2: at top of iter k, DMA
//     for tile k+2 targets buf (k-1)%3, whose reads (tile k-1) provably
//     retired during iter k-1 (in-order ds retire; last read's consumer ran)
//     -> WAR hazard gone -> NO lgkm fences; compiler pipelines ds_reads.
//   - ONE wait per tile: vmcnt(63). At the wait, DMA-k has >63 newer vmem ops
//     (stores k-2 [64], DMA k+1 [16], stores k-1 [64]) -> outstanding<=63
//     guarantees tile k landed. Steady-state outstanding << 63 -> wait ~free;
//     stores are never drained.

#define SB 16
#define SS 2048
#define SD 1024
#define TILE 64
#define NT (SS / TILE)   // 32 tiles

typedef const __attribute__((address_space(1))) void* gas_ptr;
typedef __attribute__((address_space(3))) void* las_ptr;

__global__ __launch_bounds__(64, 1) void lif_kernel(
    const float* __restrict__ x,
    const float* __restrict__ beta_mem_p,
    const float* __restrict__ beta_syn_p,
    const float* __restrict__ adapt_p,
    const float* __restrict__ scale_p,
    const float* __restrict__ lth_p,
    float* __restrict__ out)
{
#pragma clang fp contract(off)
    __shared__ __attribute__((aligned(16))) float lds[3][TILE][64];   // 48 KB

    const int bk   = blockIdx.x;           // 0..255
    const int b    = bk >> 4;              // batch
    const int d0   = (bk & 15) << 6;       // first of this block's 64 d's
    const int lane = threadIdx.x;          // 0..63
    const int d    = d0 + lane;

    const float beta_mem = beta_mem_p[0];
    const float beta_syn = beta_syn_p[0];
    const float p        = adapt_p[0];
    const float scale    = scale_p[d];
    const float lth      = lth_p[d];

    const float* xb   = x   + ((size_t)b * SS) * SD + d0;
    float*       outb = out + ((size_t)b * SS) * SD + d0;   // uniform base

    const int srow = lane >> 4;            // 0..3
    const int scol = (lane & 15) << 2;     // 0,4,...,60
    const float* src_base = xb + (size_t)srow * SD + scol;

    auto issue_tile = [&](int k, int buf) {
        const float* s0 = src_base + (size_t)(k * TILE) * SD;
        float* dst = &lds[buf][0][0];
        #pragma unroll
        for (int r = 0; r < 16; ++r) {
            __builtin_amdgcn_global_load_lds(
                (gas_ptr)(s0 + (size_t)(r * 4) * SD),
                (las_ptr)(dst + r * 4 * 64),
                16, 0, 0);
        }
    };

    float mem = 0.f, syn = 0.f, tha = 0.f, refr = 0.f;
    int sidx = lane;                       // 32-bit store index

    // FROZEN numerics (value-identical lean form, verified absmax 0.0)
    auto step = [&](float xt) {
        syn = __builtin_fmaf(beta_syn, syn, xt);
        const bool  nref    = (refr <= 0.f);
        const float syn_eff = nref ? syn : 0.f;              // syn * nonref
        mem = __builtin_fmaf(beta_mem, mem, syn_eff);
        const float q      = p * tha;
        const float cur_th = __builtin_fmaf(q, scale, lth);
        const bool  fired  = (mem >= cur_th);
        const float spike  = fired ? 1.f : 0.f;
        mem = mem - (fired ? cur_th : 0.f);                  // mem - spike*cur_th
        tha = __builtin_fmaf(0.9f, tha, fired ? 0.1f : 0.f); // +0.1*spike
        const float rnext = fmaxf(refr - 1.f, 0.f);
        refr = fired ? 2.0f : rnext;
        outb[sidx] = spike;
        sidx += SD;
    };

    // prologue: stage tiles 0,1 into bufs 0,1 (tile 2 staged in iter 0)
    issue_tile(0, 0);
    issue_tile(1, 1);
    // tile 0 landed: 16 newer ops (DMA 1) -> vmcnt(16) exact
    asm volatile("s_waitcnt vmcnt(16)" ::: "memory");

    int cbuf = 0;                           // k % 3 without div
    for (int k = 0; k < NT; ++k) {
        // tile k landed (header proof); ~free in steady state
        asm volatile("s_waitcnt vmcnt(63)" ::: "memory");
        __builtin_amdgcn_sched_barrier(0);

        // prefetch tile k+2 into buf (k+2)%3 == (k-1)%3: reads of tile k-1
        // retired during iter k-1 -> WAR-safe with no fence. (k=0: buf 2 fresh)
        if (k + 2 < NT) {
            const int nbuf = (cbuf + 2 >= 3) ? cbuf - 1 : cbuf + 2;
            issue_tile(k + 2, nbuf);
        }

        // whole 64-step x-tile into registers (static indexing); compiler
        // inserts counted lgkm waits and pipelines reads under steps
        float xa[16], xbv[16], xc[16], xd[16];
        #pragma unroll
        for (int i = 0; i < 16; ++i) xa[i]  = lds[cbuf][i][lane];
        #pragma unroll
        for (int i = 0; i < 16; ++i) xbv[i] = lds[cbuf][16 + i][lane];
        #pragma unroll
        for (int i = 0; i < 16; ++i) xc[i]  = lds[cbuf][32 + i][lane];
        #pragma unroll
        for (int i = 0; i < 16; ++i) xd[i]  = lds[cbuf][48 + i][lane];

        #pragma unroll
        for (int i = 0; i < 16; ++i) step(xa[i]);
        #pragma unroll
        for (int i = 0; i < 16; ++i) step(xbv[i]);
        #pragma unroll
        for (int i = 0; i < 16; ++i) step(xc[i]);
        #pragma unroll
        for (int i = 0; i < 16; ++i) step(xd[i]);

        cbuf = (cbuf == 2) ? 0 : cbuf + 1;
    }

    // final carry: membrane, synaptic, th_adapt, refractory (each B x D)
    const size_t base = (size_t)SB * SS * SD;
    const size_t off  = (size_t)b * SD + d;
    out[base + 0 * (size_t)SB * SD + off] = mem;
    out[base + 1 * (size_t)SB * SD + off] = syn;
    out[base + 2 * (size_t)SB * SD + off] = tha;
    out[base + 3 * (size_t)SB * SD + off] = refr;
}

extern "C" void kernel_launch(void* const* d_in, const int* in_sizes, int n_in,
                              void* d_out, int out_size, void* d_ws, size_t ws_size,
                              hipStream_t stream) {
    const float* x        = (const float*)d_in[0];
    const float* beta_mem = (const float*)d_in[1];
    const float* beta_syn = (const float*)d_in[2];
    const float* adapt_p  = (const float*)d_in[3];
    const float* scale    = (const float*)d_in[4];
    const float* lth      = (const float*)d_in[5];
    float* out = (float*)d_out;

    // 16384 chains / 64 threads = 256 blocks -> 1 wave per CU, 1 block/CU
    lif_kernel<<<256, 64, 0, stream>>>(x, beta_mem, beta_syn, adapt_p, scale, lth, out);
}

// Round 9
// 79.491 us; speedup vs baseline: 1.1405x; 1.1405x over previous
//
#include <hip/hip_runtime.h>
#include <stdint.h>

// LIF neuron scan: B=16, S=2048, D=1024, fp32. NUMERICS FROZEN (absmax 0.0):
// XLA-contracted fp32 — __builtin_fmaf at syn/mem/tha sites, contract(off)
// elsewhere; selects value-identical to mul-by-{0,1}. fp ops unchanged here.
//
// R8 post-mortem: 86-93us across 5 staging schemes -> limiter is the serial
// wave's per-step issue (step math + store + addressing + waits), not staging.
// R9: true wave specialization.
//   wave0 (consumer): ZERO vmem in loop. step = 11 VALU + 1 ds_read(x) +
//     1 ds_write(spike). Refractory tracked as lane-mask bools
//     (nref = !(fired|f1), proven == refr<=0; SALU pipe, not VALU);
//     final refr = f1?2:(f2?1:0) exactly.
//   wave1 (helper): issues x DMA (global_load_lds, own vmcnt domain) and
//     stores spikes from padded LDS ring sbuf[2][64][65] (2-way bank = free).
//   __syncthreads per tile: helper-side vmcnt(0) proves DMA k+1 landed;
//   helper work ~400cy << consumer ~2000cy/tile, so consumer never waits.

#define SB 16
#define SS 2048
#define SD 1024
#define TILE 64
#define NT (SS / TILE)   // 32 tiles

typedef const __attribute__((address_space(1))) void* gas_ptr;
typedef __attribute__((address_space(3))) void* las_ptr;

__global__ __launch_bounds__(128, 1) void lif_kernel(
    const float* __restrict__ x,
    const float* __restrict__ beta_mem_p,
    const float* __restrict__ beta_syn_p,
    const float* __restrict__ adapt_p,
    const float* __restrict__ scale_p,
    const float* __restrict__ lth_p,
    float* __restrict__ out)
{
#pragma clang fp contract(off)
    __shared__ __attribute__((aligned(16))) float xbuf[3][TILE][64];  // 48 KB
    __shared__ float sbuf[2][64][TILE + 1];                           // 33 KB

    const int bk = blockIdx.x;           // 0..255
    const int b  = bk >> 4;              // batch
    const int d0 = (bk & 15) << 6;       // first of this block's 64 d's

    if (threadIdx.x < 64) {
        // ================= consumer wave: pure compute =================
        const int lane = threadIdx.x;
        const int d    = d0 + lane;

        const float beta_mem = beta_mem_p[0];
        const float beta_syn = beta_syn_p[0];
        const float p        = adapt_p[0];
        const float scale    = scale_p[d];
        const float lth      = lth_p[d];

        float mem = 0.f, syn = 0.f, tha = 0.f;
        bool  nref = true;                 // refr<=0 at t=0
        bool  f1 = false, f2 = false;      // fired at t-1 / t-2

        __syncthreads();                   // tile 0 staged (helper prologue)

        int cbuf = 0;
        for (int k = 0; k < NT; ++k) {
            const int sb = k & 1;

            // whole 64-step x-tile into registers (static indexing)
            float xa[16], xbv[16], xc[16], xd[16];
            #pragma unroll
            for (int i = 0; i < 16; ++i) xa[i]  = xbuf[cbuf][i][lane];
            #pragma unroll
            for (int i = 0; i < 16; ++i) xbv[i] = xbuf[cbuf][16 + i][lane];
            #pragma unroll
            for (int i = 0; i < 16; ++i) xc[i]  = xbuf[cbuf][32 + i][lane];
            #pragma unroll
            for (int i = 0; i < 16; ++i) xd[i]  = xbuf[cbuf][48 + i][lane];

            // FROZEN numerics; refractory as masks (proven identical)
            auto step = [&](float xt, int ti) {
                syn = __builtin_fmaf(beta_syn, syn, xt);
                const float syn_eff = nref ? syn : 0.f;       // syn*nonref
                mem = __builtin_fmaf(beta_mem, mem, syn_eff);
                const float q      = p * tha;
                const float cur_th = __builtin_fmaf(q, scale, lth);
                const bool  fired  = (mem >= cur_th);
                const float spike  = fired ? 1.f : 0.f;
                mem = mem - (fired ? cur_th : 0.f);           // -spike*cur_th
                tha = __builtin_fmaf(0.9f, tha, fired ? 0.1f : 0.f);
                nref = !(fired || f1);                        // refr<=0 next
                f2 = f1; f1 = fired;
                sbuf[sb][lane][ti] = spike;
            };

            #pragma unroll
            for (int i = 0; i < 16; ++i) step(xa[i], i);
            #pragma unroll
            for (int i = 0; i < 16; ++i) step(xbv[i], 16 + i);
            #pragma unroll
            for (int i = 0; i < 16; ++i) step(xc[i], 32 + i);
            #pragma unroll
            for (int i = 0; i < 16; ++i) step(xd[i], 48 + i);

            __syncthreads();               // spikes visible; next x staged
            cbuf = (cbuf == 2) ? 0 : cbuf + 1;
        }

        // final carry: membrane, synaptic, th_adapt, refractory (each B x D)
        const float refr = f1 ? 2.0f : (f2 ? 1.0f : 0.0f);
        const size_t base = (size_t)SB * SS * SD;
        const size_t off  = (size_t)b * SD + d;
        out[base + 0 * (size_t)SB * SD + off] = mem;
        out[base + 1 * (size_t)SB * SD + off] = syn;
        out[base + 2 * (size_t)SB * SD + off] = tha;
        out[base + 3 * (size_t)SB * SD + off] = refr;
    } else {
        // ================= helper wave: all vmem =================
        const int hl = threadIdx.x - 64;   // 0..63

        const float* xb   = x   + ((size_t)b * SS) * SD + d0;
        float*       outb = out + ((size_t)b * SS) * SD + d0;  // uniform base

        // DMA map: call r stages rows 4r..4r+3; lane hl -> row 4r+(hl>>4),
        // cols ((hl&15)*4..+3); LDS dest = uniform base + hl*16 (linear).
        const int srow = hl >> 4;
        const int scol = (hl & 15) << 2;
        const float* src_base = xb + (size_t)srow * SD + scol;

        auto issue_tile = [&](int k, int buf) {
            const float* s0 = src_base + (size_t)(k * TILE) * SD;
            float* dst = &xbuf[buf][0][0];
            #pragma unroll
            for (int r = 0; r < 16; ++r) {
                __builtin_amdgcn_global_load_lds(
                    (gas_ptr)(s0 + (size_t)(r * 4) * SD),
                    (las_ptr)(dst + r * 4 * 64),
                    16, 0, 0);
            }
        };

        auto store_tile = [&](int tk) {    // spikes of tile tk -> global
            const int sb = tk & 1;
            int idx = tk * TILE * SD + hl; // 32-bit index from uniform base
            #pragma unroll 8
            for (int t = 0; t < TILE; ++t) {
                outb[idx] = sbuf[sb][hl][t];
                idx += SD;
            }
        };

        issue_tile(0, 0);
        issue_tile(1, 1);
        __syncthreads();                   // vmcnt(0): tiles 0,1 landed

        int nbuf = 2;
        for (int k = 0; k < NT; ++k) {
            if (k + 2 < NT) {
                issue_tile(k + 2, nbuf);   // overwrites buf read in iter k-1
                nbuf = (nbuf == 2) ? 0 : nbuf + 1;
            }
            if (k >= 1) store_tile(k - 1);
            __syncthreads();               // vmcnt(0): DMA k+1 landed
        }
        store_tile(NT - 1);
    }
}

extern "C" void kernel_launch(void* const* d_in, const int* in_sizes, int n_in,
                              void* d_out, int out_size, void* d_ws, size_t ws_size,
                              hipStream_t stream) {
    const float* x        = (const float*)d_in[0];
    const float* beta_mem = (const float*)d_in[1];
    const float* beta_syn = (const float*)d_in[2];
    const float* adapt_p  = (const float*)d_in[3];
    const float* scale    = (const float*)d_in[4];
    const float* lth      = (const float*)d_in[5];
    float* out = (float*)d_out;

    // 256 blocks x 128 threads: consumer wave + helper wave per block
    lif_kernel<<<256, 128, 0, stream>>>(x, beta_mem, beta_syn, adapt_p, scale, lth, out);
}